// Round 11
// baseline (502.328 us; speedup 1.0000x reference)
//
#include <hip/hip_runtime.h>
#include <math.h>

#define NEG_SLOPE 0.2f
#define NBUCK 512      // dst buckets of 256 nodes
#define BHCHUNK 8192   // edges per histogram block
#define BCHUNK 4096    // edges per k_bin block
#define PCAP 8192      // LDS sort capacity per bucket (mean 4096, sigma 64)

typedef __attribute__((ext_vector_type(8))) short short8;   // 8 bf16 (MFMA A/B frag)
typedef __attribute__((ext_vector_type(4))) float f32x4;    // MFMA C/D frag

__device__ __forceinline__ unsigned short bf16rne(float x) {
    unsigned u = __float_as_uint(x);
    u += 0x7fffu + ((u >> 16) & 1u);
    return (unsigned short)(u >> 16);
}
__device__ __forceinline__ unsigned pack_bf2(float x, float y) {
    unsigned ux = __float_as_uint(x), uy = __float_as_uint(y);
    ux = (ux + 0x7fffu + ((ux >> 16) & 1u)) >> 16;
    uy = (uy + 0x7fffu + ((uy >> 16) & 1u)) & 0xffff0000u;
    return ux | uy;
}

// ---------------- fused front: bucket-hist + x->bf16 + W->Wt ----------------
__global__ __launch_bounds__(256) void k_front(
    const int* __restrict__ dst, int* __restrict__ bcnt, int E,
    const float4* __restrict__ x, uint4* __restrict__ Xb, int n8,
    const float* __restrict__ w0, const float* __restrict__ w1,
    const float* __restrict__ w2, unsigned short* __restrict__ Wt,
    int nbB, int nbCvt) {
    __shared__ int cnt[NBUCK];
    int bb = blockIdx.x, t = threadIdx.x;
    if (bb < nbB) {
        for (int i = t; i < NBUCK; i += 256) cnt[i] = 0;
        __syncthreads();
        int e0 = bb * BHCHUNK;
        int n = min(BHCHUNK, E - e0);
        for (int i = t; i < n; i += 256) atomicAdd(&cnt[dst[e0 + i] >> 8], 1);
        __syncthreads();
        for (int i = t; i < NBUCK; i += 256)
            if (cnt[i]) atomicAdd(&bcnt[i], cnt[i]);
    } else if (bb < nbB + nbCvt) {
        int id = (bb - nbB) * 256 + t;
        if (id < n8) {
            float4 a = x[id * 2], b = x[id * 2 + 1];
            uint4 o;
            o.x = pack_bf2(a.x, a.y);
            o.y = pack_bf2(a.z, a.w);
            o.z = pack_bf2(b.x, b.y);
            o.w = pack_bf2(b.z, b.w);
            Xb[id] = o;
        }
    } else {
        int id = (bb - nbB - nbCvt) * 256 + t;    // 3*16384 ids
        int layer = id >> 14, rem = id & 16383;
        int k = rem >> 7, n = rem & 127;
        const float* W = (layer == 0) ? w0 : (layer == 1) ? w1 : w2;
        Wt[layer * 16384 + n * 128 + k] = bf16rne(W[k * 128 + n]);
    }
}

// ---------------- bucket scan (one block, 512 threads) ----------------
__global__ void k_bscan(const int* __restrict__ bcnt, int* __restrict__ bbase,
                        int* __restrict__ bcur, int* __restrict__ rowstart,
                        int N, int E) {
    __shared__ int sd[NBUCK];
    int t = threadIdx.x;
    int c = bcnt[t];
    sd[t] = c;
    __syncthreads();
    for (int s = 1; s < NBUCK; s <<= 1) {
        int x = (t >= s) ? sd[t - s] : 0;
        __syncthreads();
        sd[t] += x;
        __syncthreads();
    }
    int excl = sd[t] - c;
    bbase[t] = excl;
    bcur[t] = excl;
    if (t == NBUCK - 1) bbase[NBUCK] = excl + c;   // == E
    if (t == 0) rowstart[N] = E;
}

// ---------------- bin edges into buckets (contiguous packed runs) ----------------
__global__ __launch_bounds__(256) void k_bin(
    const int* __restrict__ src, const int* __restrict__ dst,
    int* __restrict__ bcur, unsigned* __restrict__ packed, int E) {
    __shared__ int cnt[NBUCK];
    __shared__ int gbase[NBUCK];
    for (int i = threadIdx.x; i < NBUCK; i += 256) cnt[i] = 0;
    __syncthreads();
    int e0 = blockIdx.x * BCHUNK;
    int n = min(BCHUNK, E - e0);
    for (int i = threadIdx.x; i < n; i += 256)
        atomicAdd(&cnt[dst[e0 + i] >> 8], 1);
    __syncthreads();
    for (int i = threadIdx.x; i < NBUCK; i += 256) {
        int c = cnt[i];
        gbase[i] = c ? atomicAdd(&bcur[i], c) : 0;
        cnt[i] = 0;
    }
    __syncthreads();
    for (int i = threadIdx.x; i < n; i += 256) {
        int d = dst[e0 + i];
        int b = d >> 8;
        int o = atomicAdd(&cnt[b], 1);
        packed[gbase[b] + o] = ((unsigned)src[e0 + i] << 8) | (unsigned)(d & 255);
    }
}

// ---------------- per-bucket: node hist + scan -> rowstart; place + SORT ----
// cpack entry = (dst_local<<17) | src  (src < 2^17).
// Rows are fully src-sorted (r9 proved -23us on aggr: with sorted rows the
// chip-wide gather hot-set is a thin sliver sweeping the F table, which L2
// holds; r10 proved coarse binning does NOT work - fine order is required).
// Unlike r9's 112us global-memory insertion sort, this sorts in LDS: place
// into a 32KB bucket buffer, per-thread insertion sort of own row (~4cyc/op),
// coalesced write-back. Fallback to unsorted global placement if a bucket
// exceeds PCAP (P~0; correctness-only guard, order is math-invariant).
__global__ __launch_bounds__(256) void k_place2(
    const unsigned* __restrict__ packed, const int* __restrict__ bbase,
    int* __restrict__ rowstart, unsigned* __restrict__ cpack, int N) {
    __shared__ int cnt[256], sd[256], lcur[256];
    __shared__ unsigned lbuf[PCAP];
    int b = blockIdx.x, t = threadIdx.x;
    int base = bbase[b], end = bbase[b + 1];
    int n = end - base;
    cnt[t] = 0;
    __syncthreads();
    for (int i = base + t; i < end; i += 256)
        atomicAdd(&cnt[packed[i] & 255u], 1);
    __syncthreads();
    sd[t] = cnt[t];
    __syncthreads();
    for (int s = 1; s < 256; s <<= 1) {
        int x = (t >= s) ? sd[t - s] : 0;
        __syncthreads();
        sd[t] += x;
        __syncthreads();
    }
    int excl = sd[t] - cnt[t];
    int gid = (b << 8) + t;
    if (gid < N) rowstart[gid] = base + excl;
    lcur[t] = excl;                    // LOCAL (0-based) cursor
    __syncthreads();
    if (n <= PCAP) {
        for (int i = base + t; i < end; i += 256) {
            unsigned p = packed[i];
            unsigned dl = p & 255u;
            int pos = atomicAdd(&lcur[dl], 1);
            lbuf[pos] = (dl << 17) | (p >> 8);
        }
        __syncthreads();
        // per-thread insertion sort of own row in LDS (dl constant per row ->
        // word order == src order)
        int rbeg = excl, rend = sd[t];
        for (int i = rbeg + 1; i < rend; i++) {
            unsigned key = lbuf[i];
            int j = i - 1;
            while (j >= rbeg && lbuf[j] > key) { lbuf[j + 1] = lbuf[j]; j--; }
            lbuf[j + 1] = key;
        }
        __syncthreads();
        for (int i = t; i < n; i += 256) cpack[base + i] = lbuf[i];   // coalesced
    } else {
        for (int i = base + t; i < end; i += 256) {
            unsigned p = packed[i];
            unsigned dl = p & 255u;
            int pos = atomicAdd(&lcur[dl], 1);
            cpack[base + pos] = (dl << 17) | (p >> 8);
        }
    }
}

// ---------------- MFMA GEMM v2 + el/er epilogue (r8 form, unchanged) -------
__global__ __launch_bounds__(256) void k_gemm(
    const unsigned short* __restrict__ Ab,   // [M][128] bf16
    const unsigned short* __restrict__ Wt,   // [128 n][128 k] bf16
    const float* __restrict__ alv, const float* __restrict__ arv,
    unsigned short* __restrict__ Fb,         // [M][128] bf16
    float* __restrict__ el, float* __restrict__ er, int M) {
    __shared__ unsigned short wls[128][136];   // padded; reused for C-staging
    int t = threadIdx.x;
    int wv = t >> 6, l = t & 63;
    int l15 = l & 15, quad = l >> 4;
    int row0 = blockIdx.x * 128 + wv * 32;

    union U { uint4 u; short8 s; };

    // A prefetch: issue all 8 global loads first (latency hides under W-stage)
    int rA0 = min(row0 + l15, M - 1);
    int rA1 = min(row0 + 16 + l15, M - 1);
    const uint4* pA0 = (const uint4*)(Ab + (size_t)rA0 * 128) + quad;
    const uint4* pA1 = (const uint4*)(Ab + (size_t)rA1 * 128) + quad;
    U A0[4], A1[4];
#pragma unroll
    for (int ks = 0; ks < 4; ks++) {
        A0[ks].u = pA0[ks * 4];
        A1[ks].u = pA1[ks * 4];
    }

    // stage Wt (32KB) -> wls, coalesced global reads, 2-way-free LDS writes
    {
        const uint4* gw = (const uint4*)Wt;
        uint4 wtmp[8];
#pragma unroll
        for (int it = 0; it < 8; it++) wtmp[it] = gw[it * 256 + t];
#pragma unroll
        for (int it = 0; it < 8; it++) {
            int flat = it * 256 + t;       // 0..2047
            int r = flat >> 4, c = flat & 15;
            *(uint4*)&wls[r][c * 8] = wtmp[it];
        }
    }
    __syncthreads();

    f32x4 acc[2][8];
#pragma unroll
    for (int mi = 0; mi < 2; mi++)
#pragma unroll
        for (int nt = 0; nt < 8; nt++)
            acc[mi][nt] = (f32x4){0.f, 0.f, 0.f, 0.f};

#pragma unroll
    for (int ks = 0; ks < 4; ks++) {
        U b[8];
#pragma unroll
        for (int nt = 0; nt < 8; nt++)
            b[nt].u = *(const uint4*)&wls[nt * 16 + l15][(quad + ks * 4) * 8];
#pragma unroll
        for (int nt = 0; nt < 8; nt++) {
            acc[0][nt] = __builtin_amdgcn_mfma_f32_16x16x32_bf16(A0[ks].s, b[nt].s, acc[0][nt], 0, 0, 0);
            acc[1][nt] = __builtin_amdgcn_mfma_f32_16x16x32_bf16(A1[ks].s, b[nt].s, acc[1][nt], 0, 0, 0);
        }
    }

    __syncthreads();   // all waves done reading W; reuse wls for C-staging
    unsigned short (*cst)[136] = (unsigned short (*)[136])&wls[wv * 32][0];

#pragma unroll
    for (int mi = 0; mi < 2; mi++)
#pragma unroll
        for (int nt = 0; nt < 8; nt++)
#pragma unroll
            for (int r = 0; r < 4; r++)
                cst[mi * 16 + quad * 4 + r][nt * 16 + l15] = bf16rne(acc[mi][nt][r]);

    int rrow = l >> 1;
    int cb = (l & 1) * 64;
    int grow = row0 + rrow;
    bool ok = grow < M;
    float pe[2] = {0.f, 0.f}, pr[2] = {0.f, 0.f};
#pragma unroll
    for (int i = 0; i < 8; i++) {
        uint4 v = *(const uint4*)&cst[rrow][cb + i * 8];
        if (ok) ((uint4*)(Fb + (size_t)grow * 128 + cb))[i] = v;
        int hi = i >> 2;
        int c0 = cb + i * 8;
        unsigned uu[4] = {v.x, v.y, v.z, v.w};
#pragma unroll
        for (int q = 0; q < 4; q++) {
            float fa = __uint_as_float(uu[q] << 16);
            float fb = __uint_as_float(uu[q] & 0xffff0000u);
            pe[hi] += fa * alv[c0 + 2 * q] + fb * alv[c0 + 2 * q + 1];
            pr[hi] += fa * arv[c0 + 2 * q] + fb * arv[c0 + 2 * q + 1];
        }
    }
    float qe0 = __shfl_xor(pe[0], 1, 64), qe1 = __shfl_xor(pe[1], 1, 64);
    float qr0 = __shfl_xor(pr[0], 1, 64), qr1 = __shfl_xor(pr[1], 1, 64);
    if (((l & 1) == 0) && ok) {
        *(float4*)&el[(size_t)grow * 4] = make_float4(pe[0], pe[1], qe0, qe1);
        *(float4*)&er[(size_t)grow * 4] = make_float4(pr[0], pr[1], qr0, qr1);
    }
}

// ---------------- aggregation with fused edge attention (r8 form) -----------
template <int OUT_BF16>
__global__ __launch_bounds__(256) void k_aggr(
    const int* __restrict__ rowstart, const unsigned* __restrict__ cpack,
    const float* __restrict__ el, const float* __restrict__ er,
    const uint4* __restrict__ F4, void* __restrict__ outp, int N, int E) {
    int lane = threadIdx.x & 63;
    int sub = lane >> 4;           // node slot in wave
    int l16 = lane & 15;
    int h = l16 >> 2;
    int w = blockIdx.x * 16 + ((threadIdx.x >> 6) << 2) + sub;
    bool active = w < N;
    int wc = active ? w : N - 1;
    int start = rowstart[wc];
    int dg = active ? (rowstart[wc + 1] - start) : 0;
    float rr = er[(size_t)wc * 4 + h];   // dst attn term: loop-invariant

    float s_acc = 0.f;
    float a0 = 0.f, a1 = 0.f, a2 = 0.f, a3 = 0.f;
    float a4 = 0.f, a5 = 0.f, a6 = 0.f, a7 = 0.f;

    int ncc = (dg + 3) >> 2;
    int m = max(ncc, __shfl_xor(ncc, 16, 64));
    int nccmax = max(m, __shfl_xor(m, 32, 64));
    int full = dg >> 2;
    int mf = min(full, __shfl_xor(full, 16, 64));
    int minfull = min(mf, __shfl_xor(mf, 32, 64));   // wave-uniform

    auto loadc = [&](int c, uint4* fb, float* eb) {
        int j = c << 2;
        if (c < minfull) {
#pragma unroll
            for (int u = 0; u < 4; u++) {
                int e = start + j + u;
                int s = (int)(cpack[e] & 0x1ffffu);
                fb[u] = F4[(size_t)s * 16 + l16];
                eb[u] = el[(size_t)s * 4 + h];
            }
        } else {
#pragma unroll
            for (int u = 0; u < 4; u++) {
                int jj = j + u;
                int e = min(max(start + min(jj, dg - 1), 0), E - 1);
                int s = (int)(cpack[e] & 0x1ffffu);
                fb[u] = F4[(size_t)s * 16 + l16];
                float ev = el[(size_t)s * 4 + h];
                eb[u] = (jj < dg) ? ev : -1e30f;   // exp(-1e30) -> 0 for pads
            }
        }
    };
    auto consume = [&](const uint4* fb, const float* eb) {
#pragma unroll
        for (int u = 0; u < 4; u++) {
            float e = eb[u] + rr;
            e = fmaxf(e, NEG_SLOPE * e);           // leaky relu
            float p = __expf(e);
            s_acc += p;
            a0 += p * __uint_as_float(fb[u].x << 16);
            a1 += p * __uint_as_float(fb[u].x & 0xffff0000u);
            a2 += p * __uint_as_float(fb[u].y << 16);
            a3 += p * __uint_as_float(fb[u].y & 0xffff0000u);
            a4 += p * __uint_as_float(fb[u].z << 16);
            a5 += p * __uint_as_float(fb[u].z & 0xffff0000u);
            a6 += p * __uint_as_float(fb[u].w << 16);
            a7 += p * __uint_as_float(fb[u].w & 0xffff0000u);
        }
    };

    uint4 f0[4], f1[4];
    float e0[4], e1[4];
    if (nccmax > 0) {
        loadc(0, f0, e0);
        for (int c = 1; c < nccmax; c++) {
            if (c & 1) { loadc(c, f1, e1); consume(f0, e0); }
            else       { loadc(c, f0, e0); consume(f1, e1); }
        }
        if (nccmax & 1) consume(f0, e0); else consume(f1, e1);
    }

    if (!active) return;
    float inv = 1.f / (s_acc + 1e-9f);
    a0 = fmaxf(a0 * inv, 0.f); a1 = fmaxf(a1 * inv, 0.f);
    a2 = fmaxf(a2 * inv, 0.f); a3 = fmaxf(a3 * inv, 0.f);
    a4 = fmaxf(a4 * inv, 0.f); a5 = fmaxf(a5 * inv, 0.f);
    a6 = fmaxf(a6 * inv, 0.f); a7 = fmaxf(a7 * inv, 0.f);
    if (OUT_BF16) {
        uint4 pk;
        pk.x = pack_bf2(a0, a1);
        pk.y = pack_bf2(a2, a3);
        pk.z = pack_bf2(a4, a5);
        pk.w = pack_bf2(a6, a7);
        ((uint4*)outp)[(size_t)w * 16 + l16] = pk;
    } else {
        float4* op = (float4*)outp + (size_t)w * 32 + l16 * 2;
        op[0] = make_float4(a0, a1, a2, a3);
        op[1] = make_float4(a4, a5, a6, a7);
    }
}

// ---------------- launch ----------------

extern "C" void kernel_launch(void* const* d_in, const int* in_sizes, int n_in,
                              void* d_out, int out_size, void* d_ws, size_t ws_size,
                              hipStream_t stream) {
    const float* x = (const float*)d_in[0];
    const int* ei = (const int*)d_in[1];
    int N = in_sizes[0] / 128;       // 100000
    int E = in_sizes[1] / 2;         // 1600000
    const int* src = ei;
    const int* dst = ei + E;
    const float* Wm[3] = {(const float*)d_in[2], (const float*)d_in[5], (const float*)d_in[8]};
    const float* al[3] = {(const float*)d_in[3], (const float*)d_in[6], (const float*)d_in[9]};
    const float* ar[3] = {(const float*)d_in[4], (const float*)d_in[7], (const float*)d_in[10]};

    char* p = (char*)d_ws;
    auto carve = [&](size_t bytes) {
        char* r = p;
        p += (bytes + 255) & ~(size_t)255;
        return r;
    };
    unsigned short* Xb = (unsigned short*)carve((size_t)N * 128 * 2);
    unsigned short* Hb = (unsigned short*)carve((size_t)N * 128 * 2);
    unsigned short* Fb = (unsigned short*)carve((size_t)N * 128 * 2);
    unsigned short* Wt = (unsigned short*)carve((size_t)3 * 16384 * 2);
    float* el       = (float*)carve((size_t)N * 4 * 4);
    float* er       = (float*)carve((size_t)N * 4 * 4);
    int* rowstart   = (int*)carve((size_t)(N + 1) * 4);
    unsigned* cpack = (unsigned*)carve((size_t)E * 4);
    unsigned* packed= (unsigned*)carve((size_t)E * 4);
    int* bcnt       = (int*)carve((size_t)NBUCK * 4);
    int* bbase      = (int*)carve((size_t)(NBUCK + 1) * 4);
    int* bcur       = (int*)carve((size_t)NBUCK * 4);

    int NBUSED = (N + 255) >> 8;     // 391

    // ---- CSR build (once) ----
    hipMemsetAsync(bcnt, 0, NBUCK * 4, stream);
    int nbB = (E + BHCHUNK - 1) / BHCHUNK;
    int n8 = N * 128 / 8;
    int nbCvt = (n8 + 255) / 256;
    int nbPrep = (3 * 16384) / 256;
    k_front<<<nbB + nbCvt + nbPrep, 256, 0, stream>>>(
        dst, bcnt, E, (const float4*)x, (uint4*)Xb, n8,
        Wm[0], Wm[1], Wm[2], Wt, nbB, nbCvt);
    k_bscan<<<1, NBUCK, 0, stream>>>(bcnt, bbase, bcur, rowstart, N, E);
    k_bin<<<(E + BCHUNK - 1) / BCHUNK, 256, 0, stream>>>(src, dst, bcur, packed, E);
    k_place2<<<NBUSED, 256, 0, stream>>>(packed, bbase, rowstart, cpack, N);

    // ---- 3 GAT layers (edge attention fused into aggregation) ----
    int gb = (N + 127) / 128;
    int ab = (N + 15) / 16;
    k_gemm<<<gb, 256, 0, stream>>>(Xb, Wt, al[0], ar[0], Fb, el, er, N);
    k_aggr<1><<<ab, 256, 0, stream>>>(rowstart, cpack, el, er, (const uint4*)Fb, Hb, N, E);

    k_gemm<<<gb, 256, 0, stream>>>(Hb, Wt + 16384, al[1], ar[1], Fb, el, er, N);
    k_aggr<1><<<ab, 256, 0, stream>>>(rowstart, cpack, el, er, (const uint4*)Fb, Hb, N, E);

    k_gemm<<<gb, 256, 0, stream>>>(Hb, Wt + 32768, al[2], ar[2], Fb, el, er, N);
    k_aggr<0><<<ab, 256, 0, stream>>>(rowstart, cpack, el, er, (const uint4*)Fb, d_out, N, E);
}

// Round 12
// 465.480 us; speedup vs baseline: 1.0792x; 1.0792x over previous
//
#include <hip/hip_runtime.h>
#include <math.h>

#define NEG_SLOPE 0.2f
#define NBUCK 512      // dst buckets of 256 nodes
#define BHCHUNK 8192   // edges per histogram block
#define BCHUNK 4096    // edges per k_bin block

typedef __attribute__((ext_vector_type(8))) short short8;   // 8 bf16 (MFMA A/B frag)
typedef __attribute__((ext_vector_type(4))) float f32x4;    // MFMA C/D frag

__device__ __forceinline__ unsigned short bf16rne(float x) {
    unsigned u = __float_as_uint(x);
    u += 0x7fffu + ((u >> 16) & 1u);
    return (unsigned short)(u >> 16);
}
__device__ __forceinline__ unsigned pack_bf2(float x, float y) {
    unsigned ux = __float_as_uint(x), uy = __float_as_uint(y);
    ux = (ux + 0x7fffu + ((ux >> 16) & 1u)) >> 16;
    uy = (uy + 0x7fffu + ((uy >> 16) & 1u)) & 0xffff0000u;
    return ux | uy;
}

// ---------------- fused front: bucket-hist + x->bf16 + W->Wt ----------------
__global__ __launch_bounds__(256) void k_front(
    const int* __restrict__ dst, int* __restrict__ bcnt, int E,
    const float4* __restrict__ x, uint4* __restrict__ Xb, int n8,
    const float* __restrict__ w0, const float* __restrict__ w1,
    const float* __restrict__ w2, unsigned short* __restrict__ Wt,
    int nbB, int nbCvt) {
    __shared__ int cnt[NBUCK];
    int bb = blockIdx.x, t = threadIdx.x;
    if (bb < nbB) {
        for (int i = t; i < NBUCK; i += 256) cnt[i] = 0;
        __syncthreads();
        int e0 = bb * BHCHUNK;
        int n = min(BHCHUNK, E - e0);
        for (int i = t; i < n; i += 256) atomicAdd(&cnt[dst[e0 + i] >> 8], 1);
        __syncthreads();
        for (int i = t; i < NBUCK; i += 256)
            if (cnt[i]) atomicAdd(&bcnt[i], cnt[i]);
    } else if (bb < nbB + nbCvt) {
        int id = (bb - nbB) * 256 + t;
        if (id < n8) {
            float4 a = x[id * 2], b = x[id * 2 + 1];
            uint4 o;
            o.x = pack_bf2(a.x, a.y);
            o.y = pack_bf2(a.z, a.w);
            o.z = pack_bf2(b.x, b.y);
            o.w = pack_bf2(b.z, b.w);
            Xb[id] = o;
        }
    } else {
        int id = (bb - nbB - nbCvt) * 256 + t;    // 3*16384 ids
        int layer = id >> 14, rem = id & 16383;
        int k = rem >> 7, n = rem & 127;
        const float* W = (layer == 0) ? w0 : (layer == 1) ? w1 : w2;
        Wt[layer * 16384 + n * 128 + k] = bf16rne(W[k * 128 + n]);
    }
}

// ---------------- bucket scan (one block, 512 threads) ----------------
__global__ void k_bscan(const int* __restrict__ bcnt, int* __restrict__ bbase,
                        int* __restrict__ bcur, int* __restrict__ rowstart,
                        int N, int E) {
    __shared__ int sd[NBUCK];
    int t = threadIdx.x;
    int c = bcnt[t];
    sd[t] = c;
    __syncthreads();
    for (int s = 1; s < NBUCK; s <<= 1) {
        int x = (t >= s) ? sd[t - s] : 0;
        __syncthreads();
        sd[t] += x;
        __syncthreads();
    }
    int excl = sd[t] - c;
    bbase[t] = excl;
    bcur[t] = excl;
    if (t == NBUCK - 1) bbase[NBUCK] = excl + c;   // == E
    if (t == 0) rowstart[N] = E;
}

// ---------------- bin edges into buckets (contiguous packed runs) ----------------
__global__ __launch_bounds__(256) void k_bin(
    const int* __restrict__ src, const int* __restrict__ dst,
    int* __restrict__ bcur, unsigned* __restrict__ packed, int E) {
    __shared__ int cnt[NBUCK];
    __shared__ int gbase[NBUCK];
    for (int i = threadIdx.x; i < NBUCK; i += 256) cnt[i] = 0;
    __syncthreads();
    int e0 = blockIdx.x * BCHUNK;
    int n = min(BCHUNK, E - e0);
    for (int i = threadIdx.x; i < n; i += 256)
        atomicAdd(&cnt[dst[e0 + i] >> 8], 1);
    __syncthreads();
    for (int i = threadIdx.x; i < NBUCK; i += 256) {
        int c = cnt[i];
        gbase[i] = c ? atomicAdd(&bcur[i], c) : 0;
        cnt[i] = 0;
    }
    __syncthreads();
    for (int i = threadIdx.x; i < n; i += 256) {
        int d = dst[e0 + i];
        int b = d >> 8;
        int o = atomicAdd(&cnt[b], 1);
        packed[gbase[b] + o] = ((unsigned)src[e0 + i] << 8) | (unsigned)(d & 255);
    }
}

// ---------------- per-bucket: node hist + scan -> rowstart; place via LDS cursors ----
// cpack entry = (dst_local<<17) | src  (src < 2^17).
// NOTE (r9-r11): per-row src sorting / coarse binning were both tried and are
// conclusively NULL for k_aggr (FETCH pinned 223-226MB regardless of order;
// the L2 miss rate is set by per-XCD 4MB capacity vs the 25.6MB F table).
// This is the plain r8 placement - cheapest correct form.
__global__ __launch_bounds__(256) void k_place2(
    const unsigned* __restrict__ packed, const int* __restrict__ bbase,
    int* __restrict__ rowstart, unsigned* __restrict__ cpack, int N) {
    __shared__ int cnt[256], sd[256], lcur[256];
    int b = blockIdx.x, t = threadIdx.x;
    int base = bbase[b], end = bbase[b + 1];
    cnt[t] = 0;
    __syncthreads();
    for (int i = base + t; i < end; i += 256)
        atomicAdd(&cnt[packed[i] & 255u], 1);
    __syncthreads();
    sd[t] = cnt[t];
    __syncthreads();
    for (int s = 1; s < 256; s <<= 1) {
        int x = (t >= s) ? sd[t - s] : 0;
        __syncthreads();
        sd[t] += x;
        __syncthreads();
    }
    int excl = sd[t] - cnt[t];
    int gid = (b << 8) + t;
    if (gid < N) rowstart[gid] = base + excl;
    lcur[t] = base + excl;
    __syncthreads();
    for (int i = base + t; i < end; i += 256) {
        unsigned p = packed[i];
        unsigned dl = p & 255u;
        int pos = atomicAdd(&lcur[dl], 1);
        cpack[pos] = (dl << 17) | (p >> 8);
    }
}

// ---------------- MFMA GEMM v2 + el/er epilogue (r8 form) ----------------
// W staged ONCE per block into padded LDS (row stride 272B -> B-frag
// ds_read_b128 and C-epilogue reads are 2-way/free). A-frags prefetched
// before staging so HBM latency hides under the W-stage. Buffer reused for
// C-staging after a barrier. (r7->r8: ~31 -> ~24us per dispatch.)
__global__ __launch_bounds__(256) void k_gemm(
    const unsigned short* __restrict__ Ab,   // [M][128] bf16
    const unsigned short* __restrict__ Wt,   // [128 n][128 k] bf16
    const float* __restrict__ alv, const float* __restrict__ arv,
    unsigned short* __restrict__ Fb,         // [M][128] bf16
    float* __restrict__ el, float* __restrict__ er, int M) {
    __shared__ unsigned short wls[128][136];   // padded; reused for C-staging
    int t = threadIdx.x;
    int wv = t >> 6, l = t & 63;
    int l15 = l & 15, quad = l >> 4;
    int row0 = blockIdx.x * 128 + wv * 32;

    union U { uint4 u; short8 s; };

    // A prefetch: issue all 8 global loads first (latency hides under W-stage)
    int rA0 = min(row0 + l15, M - 1);
    int rA1 = min(row0 + 16 + l15, M - 1);
    const uint4* pA0 = (const uint4*)(Ab + (size_t)rA0 * 128) + quad;
    const uint4* pA1 = (const uint4*)(Ab + (size_t)rA1 * 128) + quad;
    U A0[4], A1[4];
#pragma unroll
    for (int ks = 0; ks < 4; ks++) {
        A0[ks].u = pA0[ks * 4];
        A1[ks].u = pA1[ks * 4];
    }

    // stage Wt (32KB) -> wls, coalesced global reads, 2-way-free LDS writes
    {
        const uint4* gw = (const uint4*)Wt;
        uint4 wtmp[8];
#pragma unroll
        for (int it = 0; it < 8; it++) wtmp[it] = gw[it * 256 + t];
#pragma unroll
        for (int it = 0; it < 8; it++) {
            int flat = it * 256 + t;       // 0..2047
            int r = flat >> 4, c = flat & 15;
            *(uint4*)&wls[r][c * 8] = wtmp[it];
        }
    }
    __syncthreads();

    f32x4 acc[2][8];
#pragma unroll
    for (int mi = 0; mi < 2; mi++)
#pragma unroll
        for (int nt = 0; nt < 8; nt++)
            acc[mi][nt] = (f32x4){0.f, 0.f, 0.f, 0.f};

#pragma unroll
    for (int ks = 0; ks < 4; ks++) {
        U b[8];
#pragma unroll
        for (int nt = 0; nt < 8; nt++)
            b[nt].u = *(const uint4*)&wls[nt * 16 + l15][(quad + ks * 4) * 8];
#pragma unroll
        for (int nt = 0; nt < 8; nt++) {
            acc[0][nt] = __builtin_amdgcn_mfma_f32_16x16x32_bf16(A0[ks].s, b[nt].s, acc[0][nt], 0, 0, 0);
            acc[1][nt] = __builtin_amdgcn_mfma_f32_16x16x32_bf16(A1[ks].s, b[nt].s, acc[1][nt], 0, 0, 0);
        }
    }

    __syncthreads();   // all waves done reading W; reuse wls for C-staging
    unsigned short (*cst)[136] = (unsigned short (*)[136])&wls[wv * 32][0];

#pragma unroll
    for (int mi = 0; mi < 2; mi++)
#pragma unroll
        for (int nt = 0; nt < 8; nt++)
#pragma unroll
            for (int r = 0; r < 4; r++)
                cst[mi * 16 + quad * 4 + r][nt * 16 + l15] = bf16rne(acc[mi][nt][r]);

    int rrow = l >> 1;
    int cb = (l & 1) * 64;
    int grow = row0 + rrow;
    bool ok = grow < M;
    float pe[2] = {0.f, 0.f}, pr[2] = {0.f, 0.f};
#pragma unroll
    for (int i = 0; i < 8; i++) {
        uint4 v = *(const uint4*)&cst[rrow][cb + i * 8];
        if (ok) ((uint4*)(Fb + (size_t)grow * 128 + cb))[i] = v;
        int hi = i >> 2;
        int c0 = cb + i * 8;
        unsigned uu[4] = {v.x, v.y, v.z, v.w};
#pragma unroll
        for (int q = 0; q < 4; q++) {
            float fa = __uint_as_float(uu[q] << 16);
            float fb = __uint_as_float(uu[q] & 0xffff0000u);
            pe[hi] += fa * alv[c0 + 2 * q] + fb * alv[c0 + 2 * q + 1];
            pr[hi] += fa * arv[c0 + 2 * q] + fb * arv[c0 + 2 * q + 1];
        }
    }
    float qe0 = __shfl_xor(pe[0], 1, 64), qe1 = __shfl_xor(pe[1], 1, 64);
    float qr0 = __shfl_xor(pr[0], 1, 64), qr1 = __shfl_xor(pr[1], 1, 64);
    if (((l & 1) == 0) && ok) {
        *(float4*)&el[(size_t)grow * 4] = make_float4(pe[0], pe[1], qe0, qe1);
        *(float4*)&er[(size_t)grow * 4] = make_float4(pr[0], pr[1], qr0, qr1);
    }
}

// ---------------- aggregation with fused edge attention (r8 form) -----------
// 2-buffer ping-pong, clamped tail. At its practical roofline: six structural
// variants (r1/r4/r5/r6/r8 + sorted orderings r9-r11) all land 77-79us with
// FETCH pinned 223-226MB. Demand = E x 276B = 441MB/dispatch through the
// vector path in ~78us = 5.6 TB/s effective fill on random 256B granules.
template <int OUT_BF16>
__global__ __launch_bounds__(256) void k_aggr(
    const int* __restrict__ rowstart, const unsigned* __restrict__ cpack,
    const float* __restrict__ el, const float* __restrict__ er,
    const uint4* __restrict__ F4, void* __restrict__ outp, int N, int E) {
    int lane = threadIdx.x & 63;
    int sub = lane >> 4;           // node slot in wave
    int l16 = lane & 15;
    int h = l16 >> 2;
    int w = blockIdx.x * 16 + ((threadIdx.x >> 6) << 2) + sub;
    bool active = w < N;
    int wc = active ? w : N - 1;
    int start = rowstart[wc];
    int dg = active ? (rowstart[wc + 1] - start) : 0;
    float rr = er[(size_t)wc * 4 + h];   // dst attn term: loop-invariant

    float s_acc = 0.f;
    float a0 = 0.f, a1 = 0.f, a2 = 0.f, a3 = 0.f;
    float a4 = 0.f, a5 = 0.f, a6 = 0.f, a7 = 0.f;

    int ncc = (dg + 3) >> 2;
    int m = max(ncc, __shfl_xor(ncc, 16, 64));
    int nccmax = max(m, __shfl_xor(m, 32, 64));
    int full = dg >> 2;
    int mf = min(full, __shfl_xor(full, 16, 64));
    int minfull = min(mf, __shfl_xor(mf, 32, 64));   // wave-uniform

    auto loadc = [&](int c, uint4* fb, float* eb) {
        int j = c << 2;
        if (c < minfull) {
#pragma unroll
            for (int u = 0; u < 4; u++) {
                int e = start + j + u;
                int s = (int)(cpack[e] & 0x1ffffu);
                fb[u] = F4[(size_t)s * 16 + l16];
                eb[u] = el[(size_t)s * 4 + h];
            }
        } else {
#pragma unroll
            for (int u = 0; u < 4; u++) {
                int jj = j + u;
                int e = min(max(start + min(jj, dg - 1), 0), E - 1);
                int s = (int)(cpack[e] & 0x1ffffu);
                fb[u] = F4[(size_t)s * 16 + l16];
                float ev = el[(size_t)s * 4 + h];
                eb[u] = (jj < dg) ? ev : -1e30f;   // exp(-1e30) -> 0 for pads
            }
        }
    };
    auto consume = [&](const uint4* fb, const float* eb) {
#pragma unroll
        for (int u = 0; u < 4; u++) {
            float e = eb[u] + rr;
            e = fmaxf(e, NEG_SLOPE * e);           // leaky relu
            float p = __expf(e);
            s_acc += p;
            a0 += p * __uint_as_float(fb[u].x << 16);
            a1 += p * __uint_as_float(fb[u].x & 0xffff0000u);
            a2 += p * __uint_as_float(fb[u].y << 16);
            a3 += p * __uint_as_float(fb[u].y & 0xffff0000u);
            a4 += p * __uint_as_float(fb[u].z << 16);
            a5 += p * __uint_as_float(fb[u].z & 0xffff0000u);
            a6 += p * __uint_as_float(fb[u].w << 16);
            a7 += p * __uint_as_float(fb[u].w & 0xffff0000u);
        }
    };

    uint4 f0[4], f1[4];
    float e0[4], e1[4];
    if (nccmax > 0) {
        loadc(0, f0, e0);
        for (int c = 1; c < nccmax; c++) {
            if (c & 1) { loadc(c, f1, e1); consume(f0, e0); }
            else       { loadc(c, f0, e0); consume(f1, e1); }
        }
        if (nccmax & 1) consume(f0, e0); else consume(f1, e1);
    }

    if (!active) return;
    float inv = 1.f / (s_acc + 1e-9f);
    a0 = fmaxf(a0 * inv, 0.f); a1 = fmaxf(a1 * inv, 0.f);
    a2 = fmaxf(a2 * inv, 0.f); a3 = fmaxf(a3 * inv, 0.f);
    a4 = fmaxf(a4 * inv, 0.f); a5 = fmaxf(a5 * inv, 0.f);
    a6 = fmaxf(a6 * inv, 0.f); a7 = fmaxf(a7 * inv, 0.f);
    if (OUT_BF16) {
        uint4 pk;
        pk.x = pack_bf2(a0, a1);
        pk.y = pack_bf2(a2, a3);
        pk.z = pack_bf2(a4, a5);
        pk.w = pack_bf2(a6, a7);
        ((uint4*)outp)[(size_t)w * 16 + l16] = pk;
    } else {
        float4* op = (float4*)outp + (size_t)w * 32 + l16 * 2;
        op[0] = make_float4(a0, a1, a2, a3);
        op[1] = make_float4(a4, a5, a6, a7);
    }
}

// ---------------- launch ----------------

extern "C" void kernel_launch(void* const* d_in, const int* in_sizes, int n_in,
                              void* d_out, int out_size, void* d_ws, size_t ws_size,
                              hipStream_t stream) {
    const float* x = (const float*)d_in[0];
    const int* ei = (const int*)d_in[1];
    int N = in_sizes[0] / 128;       // 100000
    int E = in_sizes[1] / 2;         // 1600000
    const int* src = ei;
    const int* dst = ei + E;
    const float* Wm[3] = {(const float*)d_in[2], (const float*)d_in[5], (const float*)d_in[8]};
    const float* al[3] = {(const float*)d_in[3], (const float*)d_in[6], (const float*)d_in[9]};
    const float* ar[3] = {(const float*)d_in[4], (const float*)d_in[7], (const float*)d_in[10]};

    char* p = (char*)d_ws;
    auto carve = [&](size_t bytes) {
        char* r = p;
        p += (bytes + 255) & ~(size_t)255;
        return r;
    };
    unsigned short* Xb = (unsigned short*)carve((size_t)N * 128 * 2);
    unsigned short* Hb = (unsigned short*)carve((size_t)N * 128 * 2);
    unsigned short* Fb = (unsigned short*)carve((size_t)N * 128 * 2);
    unsigned short* Wt = (unsigned short*)carve((size_t)3 * 16384 * 2);
    float* el       = (float*)carve((size_t)N * 4 * 4);
    float* er       = (float*)carve((size_t)N * 4 * 4);
    int* rowstart   = (int*)carve((size_t)(N + 1) * 4);
    unsigned* cpack = (unsigned*)carve((size_t)E * 4);
    unsigned* packed= (unsigned*)carve((size_t)E * 4);
    int* bcnt       = (int*)carve((size_t)NBUCK * 4);
    int* bbase      = (int*)carve((size_t)(NBUCK + 1) * 4);
    int* bcur       = (int*)carve((size_t)NBUCK * 4);

    int NBUSED = (N + 255) >> 8;     // 391

    // ---- CSR build (once) ----
    hipMemsetAsync(bcnt, 0, NBUCK * 4, stream);
    int nbB = (E + BHCHUNK - 1) / BHCHUNK;
    int n8 = N * 128 / 8;
    int nbCvt = (n8 + 255) / 256;
    int nbPrep = (3 * 16384) / 256;
    k_front<<<nbB + nbCvt + nbPrep, 256, 0, stream>>>(
        dst, bcnt, E, (const float4*)x, (uint4*)Xb, n8,
        Wm[0], Wm[1], Wm[2], Wt, nbB, nbCvt);
    k_bscan<<<1, NBUCK, 0, stream>>>(bcnt, bbase, bcur, rowstart, N, E);
    k_bin<<<(E + BCHUNK - 1) / BCHUNK, 256, 0, stream>>>(src, dst, bcur, packed, E);
    k_place2<<<NBUSED, 256, 0, stream>>>(packed, bbase, rowstart, cpack, N);

    // ---- 3 GAT layers (edge attention fused into aggregation) ----
    int gb = (N + 127) / 128;
    int ab = (N + 15) / 16;
    k_gemm<<<gb, 256, 0, stream>>>(Xb, Wt, al[0], ar[0], Fb, el, er, N);
    k_aggr<1><<<ab, 256, 0, stream>>>(rowstart, cpack, el, er, (const uint4*)Fb, Hb, N, E);

    k_gemm<<<gb, 256, 0, stream>>>(Hb, Wt + 16384, al[1], ar[1], Fb, el, er, N);
    k_aggr<1><<<ab, 256, 0, stream>>>(rowstart, cpack, el, er, (const uint4*)Fb, Hb, N, E);

    k_gemm<<<gb, 256, 0, stream>>>(Hb, Wt + 32768, al[2], ar[2], Fb, el, er, N);
    k_aggr<0><<<ab, 256, 0, stream>>>(rowstart, cpack, el, er, (const uint4*)Fb, d_out, N, E);
}